// Round 3
// baseline (93.441 us; speedup 1.0000x reference)
//
#include <hip/hip_runtime.h>
#include <hip/hip_bf16.h>

namespace {
constexpr int kH = 192, kW = 640, kHW = kH * kW;
constexpr int kHW4 = kHW / 4;           // float4 granules per image plane
constexpr int kB = 2, kC = 64;          // batch, image channels
constexpr int kN0 = 40000, kC0 = 32;    // level0 points/channels
constexpr int kN1 = 20000, kC1 = 64;    // level1 points/channels
constexpr int kCL = 67;                 // C1 + 3

// ---------------------------------------------------------------------------
// winner-index scatter (last-write-wins == max point index wins).
// Both levels in one launch; winners pre-initialized to -1 via memsetAsync.
// ---------------------------------------------------------------------------
__global__ void scatter_win(const float* __restrict__ coor0,
                            const float* __restrict__ coor1,
                            int* __restrict__ win0, int* __restrict__ win1) {
  int idx = blockIdx.x * blockDim.x + threadIdx.x;
  const float* coor;
  int* win;
  int N;
  if (idx < kB * kN0) {
    coor = coor0; win = win0; N = kN0;
  } else {
    idx -= kB * kN0;
    if (idx >= kB * kN1) return;
    coor = coor1; win = win1; N = kN1;
  }
  int b = idx / N;
  float u = coor[(size_t)idx * 2 + 0];
  float v = coor[(size_t)idx * 2 + 1];
  u = fminf(fmaxf(u, 0.f), 1.f);
  v = fminf(fmaxf(v, 0.f), 1.f);
  int r = (int)(v * (float)kH);   // row from coor[:,1]
  int c = (int)(u * (float)kW);   // col from coor[:,0]
  if (r < kH && c < kW) {
    int n = idx - b * N;
    atomicMax(&win[b * kHW + r * kW + c], n);
  }
}

// ---------------------------------------------------------------------------
// fold all linear stages into the point features (single block):
//   b'   = W2 @ b0 + b2                      [67]
//   A1   = Wsp^T @ W2                        [9,67]
//   M0   = A1 @ W0                           [9,35]
//   sb_k = Wsp[:,k] . b'                     [9]
//   ws_k = sum_c Wsp[c,k]                    [9]
// ---------------------------------------------------------------------------
__global__ __launch_bounds__(640) void kprecomp(
    const float* __restrict__ W0, const float* __restrict__ b0,
    const float* __restrict__ W2, const float* __restrict__ b2,
    const float* __restrict__ Wsp,
    float* __restrict__ M0, float* __restrict__ A1g,
    float* __restrict__ sb, float* __restrict__ wsum) {
  __shared__ float A1s[9 * kCL];
  __shared__ float bp[kCL];
  const int t = threadIdx.x;
  if (t < kCL) {
    float s = b2[t];
    for (int j = 0; j < kCL; ++j) s += W2[t * kCL + j] * b0[j];
    bp[t] = s;
  }
  if (t < 9 * kCL) {
    int k = t / kCL, j = t - k * kCL;
    float s = 0.f;
    for (int c = 0; c < kCL; ++c) s += Wsp[c * 9 + k] * W2[c * kCL + j];
    A1s[t] = s;
    A1g[t] = s;
  }
  __syncthreads();
  if (t < 9 * 35) {
    int k = t / 35, i = t - k * 35;
    float s = 0.f;
    for (int j = 0; j < kCL; ++j) s += A1s[k * kCL + j] * W0[j * 35 + i];
    M0[t] = s;
  }
  if (t >= 576 && t < 585) {
    int k = t - 576;
    float s = 0.f;
    for (int c = 0; c < kCL; ++c) s += Wsp[c * 9 + k] * bp[c];
    sb[k] = s;
  }
  if (t >= 592 && t < 601) {
    int k = t - 592;
    float s = 0.f;
    for (int c = 0; c < kCL; ++c) s += Wsp[c * 9 + k];
    wsum[k] = s;
  }
}

// ---------------------------------------------------------------------------
// gate field, float4 over pixels: g[b,p] = b3 + W3 . x_rgb[b,:,p]
// ---------------------------------------------------------------------------
__global__ __launch_bounds__(256) void kgate(const float* __restrict__ x_rgb,
                                             const float* __restrict__ W3,
                                             const float* __restrict__ b3,
                                             float* __restrict__ g) {
  const int j = blockIdx.x * 256 + threadIdx.x;  // [0, B*kHW4)
  const int b = j / kHW4;
  const int p4 = j - b * kHW4;
  const float4* xr = (const float4*)(x_rgb + (size_t)b * kC * kHW) + p4;
  float bias = b3[0];
  float4 acc = make_float4(bias, bias, bias, bias);
#pragma unroll
  for (int c = 0; c < kC; ++c) {
    float wv = W3[c];
    float4 x4 = xr[(size_t)c * kHW4];
    acc.x += wv * x4.x;
    acc.y += wv * x4.y;
    acc.z += wv * x4.z;
    acc.w += wv * x4.w;
  }
  ((float4*)g)[j] = acc;
}

// ---------------------------------------------------------------------------
// att[p] = sigmoid( bsp + sum_{valid taps k} ( wsum[k]*g[q] + sb[k]
//           + [win0[q]>=0] M0[k].p0(q) + [win1[q]>=0] A1[k].p1(q) ) )
// ---------------------------------------------------------------------------
__global__ __launch_bounds__(256) void katt(
    const float* __restrict__ g,
    const int* __restrict__ win0, const int* __restrict__ win1,
    const float* __restrict__ feat0, const float* __restrict__ vox0,
    const float* __restrict__ feat1, const float* __restrict__ vox1,
    const float* __restrict__ M0, const float* __restrict__ A1,
    const float* __restrict__ sb, const float* __restrict__ wsum,
    const float* __restrict__ bsp, float* __restrict__ att) {
  const int pix = blockIdx.x * 256 + threadIdx.x;
  const int b = pix / kHW;
  const int p = pix - b * kHW;
  const int h = p / kW;
  const int w = p - h * kW;

  float logit = bsp[0];
#pragma unroll
  for (int dh = -1; dh <= 1; ++dh) {
    const int hh = h + dh;
    if (hh < 0 || hh >= kH) continue;
#pragma unroll
    for (int dw = -1; dw <= 1; ++dw) {
      const int ww = w + dw;
      if (ww < 0 || ww >= kW) continue;
      const int k = (dh + 1) * 3 + (dw + 1);
      const int q = b * kHW + hh * kW + ww;
      logit += wsum[k] * g[q] + sb[k];
      const int w0 = win0[q];
      if (w0 >= 0) {
        const float* f0 = feat0 + ((size_t)b * kN0 + w0) * kC0;
        const float* m = M0 + k * 35;
        float s = 0.f;
#pragma unroll
        for (int i = 0; i < kC0; ++i) s += m[i] * f0[i];
        const float* v0 = vox0 + ((size_t)b * kN0 + w0) * 3;
        s += m[32] * v0[0] + m[33] * v0[1] + m[34] * v0[2];
        logit += s;
      }
      const int w1 = win1[q];
      if (w1 >= 0) {
        const float* f1 = feat1 + ((size_t)b * kN1 + w1) * kC1;
        const float* m = A1 + k * kCL;
        float s = 0.f;
#pragma unroll
        for (int i = 0; i < kC1; ++i) s += m[i] * f1[i];
        const float* v1 = vox1 + ((size_t)b * kN1 + w1) * 3;
        s += m[64] * v1[0] + m[65] * v1[1] + m[66] * v1[2];
        logit += s;
      }
    }
  }
  att[pix] = 1.f / (1.f + __expf(-logit));
}

// ---------------------------------------------------------------------------
// out[b,c,p] = x_rgb[b,c,p] * att[b,p], float4-vectorized stream
// ---------------------------------------------------------------------------
__global__ __launch_bounds__(256) void kmul(const float* __restrict__ x_rgb,
                                            const float* __restrict__ att,
                                            float* __restrict__ out) {
  const int i = blockIdx.x * 256 + threadIdx.x;  // [0, B*C*kHW4)
  const int b = i / (kC * kHW4);
  const int r = i - b * (kC * kHW4);
  const int p4 = r % kHW4;
  float4 a4 = ((const float4*)att)[b * kHW4 + p4];
  float4 x4 = ((const float4*)x_rgb)[i];
  x4.x *= a4.x;
  x4.y *= a4.y;
  x4.z *= a4.z;
  x4.w *= a4.w;
  ((float4*)out)[i] = x4;
}

}  // namespace

extern "C" void kernel_launch(void* const* d_in, const int* in_sizes, int n_in,
                              void* d_out, int out_size, void* d_ws,
                              size_t ws_size, hipStream_t stream) {
  const float* x_rgb = (const float*)d_in[0];
  const float* feat0 = (const float*)d_in[1];
  const float* coor0 = (const float*)d_in[2];
  const float* vox0 = (const float*)d_in[3];
  const float* feat1 = (const float*)d_in[4];
  const float* coor1 = (const float*)d_in[5];
  const float* vox1 = (const float*)d_in[6];
  const float* W0 = (const float*)d_in[7];
  const float* b0 = (const float*)d_in[8];
  const float* W2 = (const float*)d_in[9];
  const float* b2 = (const float*)d_in[10];
  const float* W3 = (const float*)d_in[11];
  const float* b3 = (const float*)d_in[12];
  const float* Wsp = (const float*)d_in[13];
  const float* bsp = (const float*)d_in[14];
  float* out = (float*)d_out;

  // workspace layout (all 16B aligned):
  //   g[B*HW] | att[B*HW] | win0[B*HW] | win1[B*HW] | M0 | A1 | sb | wsum
  float* g = (float*)d_ws;
  float* att = g + (size_t)kB * kHW;
  int* win0 = (int*)(att + (size_t)kB * kHW);
  int* win1 = win0 + (size_t)kB * kHW;
  float* M0 = (float*)(win1 + (size_t)kB * kHW);
  float* A1 = M0 + 9 * 35;
  float* sb = A1 + 9 * kCL;
  float* wsum = sb + 9;

  hipMemsetAsync(win0, 0xFF, (size_t)2 * kB * kHW * sizeof(int), stream);
  const int npts = kB * (kN0 + kN1);
  scatter_win<<<(npts + 255) / 256, 256, 0, stream>>>(coor0, coor1, win0,
                                                      win1);
  kprecomp<<<1, 640, 0, stream>>>(W0, b0, W2, b2, Wsp, M0, A1, sb, wsum);
  kgate<<<kB * kHW4 / 256, 256, 0, stream>>>(x_rgb, W3, b3, g);
  katt<<<kB * kHW / 256, 256, 0, stream>>>(g, win0, win1, feat0, vox0, feat1,
                                           vox1, M0, A1, sb, wsum, bsp, att);
  kmul<<<kB * kC * kHW4 / 256, 256, 0, stream>>>(x_rgb, att, out);
}

// Round 4
// 76.408 us; speedup vs baseline: 1.2229x; 1.2229x over previous
//
#include <hip/hip_runtime.h>
#include <hip/hip_bf16.h>

namespace {
constexpr int kH = 192, kW = 640, kHW = kH * kW;
constexpr int kHW4 = kHW / 4;           // float4 granules per image plane
constexpr int kB = 2, kC = 64;          // batch, image channels
constexpr int kN0 = 40000, kC0 = 32;    // level0 points/channels
constexpr int kN1 = 20000, kC1 = 64;    // level1 points/channels
constexpr int kCL = 67;                 // C1 + 3
constexpr int kBHW = kB * kHW;

// ---------------------------------------------------------------------------
// winner-index scatter (last-write-wins == max point index wins).
// Both levels in one launch; winners pre-initialized to -1 via memsetAsync.
// ---------------------------------------------------------------------------
__global__ void scatter_win(const float* __restrict__ coor0,
                            const float* __restrict__ coor1,
                            int* __restrict__ win0, int* __restrict__ win1) {
  int idx = blockIdx.x * blockDim.x + threadIdx.x;
  const float* coor;
  int* win;
  int N;
  if (idx < kB * kN0) {
    coor = coor0; win = win0; N = kN0;
  } else {
    idx -= kB * kN0;
    if (idx >= kB * kN1) return;
    coor = coor1; win = win1; N = kN1;
  }
  int b = idx / N;
  float u = coor[(size_t)idx * 2 + 0];
  float v = coor[(size_t)idx * 2 + 1];
  u = fminf(fmaxf(u, 0.f), 1.f);
  v = fminf(fmaxf(v, 0.f), 1.f);
  int r = (int)(v * (float)kH);   // row from coor[:,1]
  int c = (int)(u * (float)kW);   // col from coor[:,0]
  if (r < kH && c < kW) {
    int n = idx - b * N;
    atomicMax(&win[b * kHW + r * kW + c], n);
  }
}

// ---------------------------------------------------------------------------
// fold all linear stages into the point features (single block):
//   b'   = W2 @ b0 + b2                      [67]
//   A1   = Wsp^T @ W2                        [9,67]
//   M0   = A1 @ W0                           [9,35]
//   sb_k = Wsp[:,k] . b'                     [9]
//   ws_k = sum_c Wsp[c,k]                    [9]
// ---------------------------------------------------------------------------
__global__ __launch_bounds__(640) void kprecomp(
    const float* __restrict__ W0, const float* __restrict__ b0,
    const float* __restrict__ W2, const float* __restrict__ b2,
    const float* __restrict__ Wsp,
    float* __restrict__ M0, float* __restrict__ A1g,
    float* __restrict__ sb, float* __restrict__ wsum) {
  __shared__ float A1s[9 * kCL];
  __shared__ float bp[kCL];
  const int t = threadIdx.x;
  if (t < kCL) {
    float s = b2[t];
    for (int j = 0; j < kCL; ++j) s += W2[t * kCL + j] * b0[j];
    bp[t] = s;
  }
  if (t < 9 * kCL) {
    int k = t / kCL, j = t - k * kCL;
    float s = 0.f;
    for (int c = 0; c < kCL; ++c) s += Wsp[c * 9 + k] * W2[c * kCL + j];
    A1s[t] = s;
    A1g[t] = s;
  }
  __syncthreads();
  if (t < 9 * 35) {
    int k = t / 35, i = t - k * 35;
    float s = 0.f;
    for (int j = 0; j < kCL; ++j) s += A1s[k * kCL + j] * W0[j * 35 + i];
    M0[t] = s;
  }
  if (t >= 576 && t < 585) {
    int k = t - 576;
    float s = 0.f;
    for (int c = 0; c < kCL; ++c) s += Wsp[c * 9 + k] * bp[c];
    sb[k] = s;
  }
  if (t >= 592 && t < 601) {
    int k = t - 592;
    float s = 0.f;
    for (int c = 0; c < kCL; ++c) s += Wsp[c * 9 + k];
    wsum[k] = s;
  }
}

// ---------------------------------------------------------------------------
// gate field, float4 over pixels: g[b,p] = b3 + W3 . x_rgb[b,:,p]
// ---------------------------------------------------------------------------
__global__ __launch_bounds__(256) void kgate(const float* __restrict__ x_rgb,
                                             const float* __restrict__ W3,
                                             const float* __restrict__ b3,
                                             float* __restrict__ g) {
  const int j = blockIdx.x * 256 + threadIdx.x;  // [0, B*kHW4)
  const int b = j / kHW4;
  const int p4 = j - b * kHW4;
  const float4* xr = (const float4*)(x_rgb + (size_t)b * kC * kHW) + p4;
  float bias = b3[0];
  float4 acc = make_float4(bias, bias, bias, bias);
#pragma unroll
  for (int c = 0; c < kC; ++c) {
    float wv = W3[c];
    float4 x4 = xr[(size_t)c * kHW4];
    acc.x += wv * x4.x;
    acc.y += wv * x4.y;
    acc.z += wv * x4.z;
    acc.w += wv * x4.w;
  }
  ((float4*)g)[j] = acc;
}

// ---------------------------------------------------------------------------
// per-SOURCE-pixel tap projection (gathers happen once, not 9x):
//   y[k][pix] = wsum[k]*g[pix] + sb[k]
//             + [win0>=0] M0[k].p0(pix) + [win1>=0] A1[k].p1(pix)
// M0/A1 reads are wave-uniform constant offsets -> scalar loads.
// ---------------------------------------------------------------------------
__global__ __launch_bounds__(256) void kgy(
    const float* __restrict__ g,
    const int* __restrict__ win0, const int* __restrict__ win1,
    const float* __restrict__ feat0, const float* __restrict__ vox0,
    const float* __restrict__ feat1, const float* __restrict__ vox1,
    const float* __restrict__ M0, const float* __restrict__ A1,
    const float* __restrict__ sb, const float* __restrict__ wsum,
    float* __restrict__ y) {
  const int pix = blockIdx.x * 256 + threadIdx.x;
  const int b = pix / kHW;
  const float gv = g[pix];
  float yk[9];
#pragma unroll
  for (int k = 0; k < 9; ++k) yk[k] = wsum[k] * gv + sb[k];

  const int w0 = win0[pix];
  if (w0 >= 0) {
    const float* f0 = feat0 + ((size_t)b * kN0 + w0) * kC0;
#pragma unroll
    for (int i = 0; i < kC0; ++i) {
      float v = f0[i];
#pragma unroll
      for (int k = 0; k < 9; ++k) yk[k] += M0[k * 35 + i] * v;
    }
    const float* v0 = vox0 + ((size_t)b * kN0 + w0) * 3;
#pragma unroll
    for (int i = 0; i < 3; ++i) {
      float v = v0[i];
#pragma unroll
      for (int k = 0; k < 9; ++k) yk[k] += M0[k * 35 + kC0 + i] * v;
    }
  }
  const int w1 = win1[pix];
  if (w1 >= 0) {
    const float* f1 = feat1 + ((size_t)b * kN1 + w1) * kC1;
#pragma unroll
    for (int i = 0; i < kC1; ++i) {
      float v = f1[i];
#pragma unroll
      for (int k = 0; k < 9; ++k) yk[k] += A1[k * kCL + i] * v;
    }
    const float* v1 = vox1 + ((size_t)b * kN1 + w1) * 3;
#pragma unroll
    for (int i = 0; i < 3; ++i) {
      float v = v1[i];
#pragma unroll
      for (int k = 0; k < 9; ++k) yk[k] += A1[k * kCL + kC1 + i] * v;
    }
  }
#pragma unroll
  for (int k = 0; k < 9; ++k) y[(size_t)k * kBHW + pix] = yk[k];
}

// ---------------------------------------------------------------------------
// stencil-sum of the 9 planes (coalesced) + sigmoid:
//   att[p] = sigmoid( bsp + sum_{valid k} y[k][p + off_k] )
// ---------------------------------------------------------------------------
__global__ __launch_bounds__(256) void katt2(const float* __restrict__ y,
                                             const float* __restrict__ bsp,
                                             float* __restrict__ att) {
  const int pix = blockIdx.x * 256 + threadIdx.x;
  const int b = pix / kHW;
  const int p = pix - b * kHW;
  const int h = p / kW;
  const int w = p - h * kW;

  float logit = bsp[0];
#pragma unroll
  for (int dh = -1; dh <= 1; ++dh) {
    const int hh = h + dh;
    if (hh < 0 || hh >= kH) continue;
#pragma unroll
    for (int dw = -1; dw <= 1; ++dw) {
      const int ww = w + dw;
      if (ww < 0 || ww >= kW) continue;
      const int k = (dh + 1) * 3 + (dw + 1);
      logit += y[(size_t)k * kBHW + b * kHW + hh * kW + ww];
    }
  }
  att[pix] = 1.f / (1.f + __expf(-logit));
}

// ---------------------------------------------------------------------------
// out[b,c,p] = x_rgb[b,c,p] * att[b,p], float4-vectorized stream
// ---------------------------------------------------------------------------
__global__ __launch_bounds__(256) void kmul(const float* __restrict__ x_rgb,
                                            const float* __restrict__ att,
                                            float* __restrict__ out) {
  const int i = blockIdx.x * 256 + threadIdx.x;  // [0, B*C*kHW4)
  const int b = i / (kC * kHW4);
  const int r = i - b * (kC * kHW4);
  const int p4 = r % kHW4;
  float4 a4 = ((const float4*)att)[b * kHW4 + p4];
  float4 x4 = ((const float4*)x_rgb)[i];
  x4.x *= a4.x;
  x4.y *= a4.y;
  x4.z *= a4.z;
  x4.w *= a4.w;
  ((float4*)out)[i] = x4;
}

}  // namespace

extern "C" void kernel_launch(void* const* d_in, const int* in_sizes, int n_in,
                              void* d_out, int out_size, void* d_ws,
                              size_t ws_size, hipStream_t stream) {
  const float* x_rgb = (const float*)d_in[0];
  const float* feat0 = (const float*)d_in[1];
  const float* coor0 = (const float*)d_in[2];
  const float* vox0 = (const float*)d_in[3];
  const float* feat1 = (const float*)d_in[4];
  const float* coor1 = (const float*)d_in[5];
  const float* vox1 = (const float*)d_in[6];
  const float* W0 = (const float*)d_in[7];
  const float* b0 = (const float*)d_in[8];
  const float* W2 = (const float*)d_in[9];
  const float* b2 = (const float*)d_in[10];
  const float* W3 = (const float*)d_in[11];
  const float* b3 = (const float*)d_in[12];
  const float* Wsp = (const float*)d_in[13];
  const float* bsp = (const float*)d_in[14];
  float* out = (float*)d_out;

  // workspace layout (all 16B aligned):
  //   g[BHW] | att[BHW] | y[9*BHW] | win0[BHW] | win1[BHW] | M0 | A1 | sb | ws
  float* g = (float*)d_ws;
  float* att = g + (size_t)kBHW;
  float* y = att + (size_t)kBHW;
  int* win0 = (int*)(y + (size_t)9 * kBHW);
  int* win1 = win0 + (size_t)kBHW;
  float* M0 = (float*)(win1 + (size_t)kBHW);
  float* A1 = M0 + 9 * 35;
  float* sb = A1 + 9 * kCL;
  float* wsum = sb + 9;

  hipMemsetAsync(win0, 0xFF, (size_t)2 * kBHW * sizeof(int), stream);
  const int npts = kB * (kN0 + kN1);
  scatter_win<<<(npts + 255) / 256, 256, 0, stream>>>(coor0, coor1, win0,
                                                      win1);
  kprecomp<<<1, 640, 0, stream>>>(W0, b0, W2, b2, Wsp, M0, A1, sb, wsum);
  kgate<<<kB * kHW4 / 256, 256, 0, stream>>>(x_rgb, W3, b3, g);
  kgy<<<kBHW / 256, 256, 0, stream>>>(g, win0, win1, feat0, vox0, feat1, vox1,
                                      M0, A1, sb, wsum, y);
  katt2<<<kBHW / 256, 256, 0, stream>>>(y, bsp, att);
  kmul<<<kB * kC * kHW4 / 256, 256, 0, stream>>>(x_rgb, att, out);
}

// Round 5
// 76.268 us; speedup vs baseline: 1.2252x; 1.0018x over previous
//
#include <hip/hip_runtime.h>
#include <hip/hip_bf16.h>

namespace {
constexpr int kH = 192, kW = 640, kHW = kH * kW;
constexpr int kHW4 = kHW / 4;           // float4 granules per image plane
constexpr int kB = 2, kC = 64;          // batch, image channels
constexpr int kN0 = 40000, kC0 = 32;    // level0 points/channels
constexpr int kN1 = 20000, kC1 = 64;    // level1 points/channels
constexpr int kCL = 67;                 // C1 + 3
constexpr int kBHW = kB * kHW;

// ---------------------------------------------------------------------------
// fast -1 fill for the two winner maps (2*kBHW ints, int4-vectorized).
// hipMemsetAsync's fill kernel measured 49 GB/s (40us for 2MB) -- replace.
// ---------------------------------------------------------------------------
__global__ __launch_bounds__(256) void kwinit(int4* __restrict__ w, int n4) {
  int i = blockIdx.x * 256 + threadIdx.x;
  if (i < n4) w[i] = make_int4(-1, -1, -1, -1);
}

// ---------------------------------------------------------------------------
// winner-index scatter (last-write-wins == max point index wins).
// ---------------------------------------------------------------------------
__global__ void scatter_win(const float* __restrict__ coor0,
                            const float* __restrict__ coor1,
                            int* __restrict__ win0, int* __restrict__ win1) {
  int idx = blockIdx.x * blockDim.x + threadIdx.x;
  const float* coor;
  int* win;
  int N;
  if (idx < kB * kN0) {
    coor = coor0; win = win0; N = kN0;
  } else {
    idx -= kB * kN0;
    if (idx >= kB * kN1) return;
    coor = coor1; win = win1; N = kN1;
  }
  int b = idx / N;
  float u = coor[(size_t)idx * 2 + 0];
  float v = coor[(size_t)idx * 2 + 1];
  u = fminf(fmaxf(u, 0.f), 1.f);
  v = fminf(fmaxf(v, 0.f), 1.f);
  int r = (int)(v * (float)kH);   // row from coor[:,1]
  int c = (int)(u * (float)kW);   // col from coor[:,0]
  if (r < kH && c < kW) {
    int n = idx - b * N;
    atomicMax(&win[b * kHW + r * kW + c], n);
  }
}

// ---------------------------------------------------------------------------
// fold all linear stages into the point features (single block):
//   b'   = W2 @ b0 + b2                      [67]
//   A1   = Wsp^T @ W2                        [9,67]
//   M0   = A1 @ W0                           [9,35]
//   sb_k = Wsp[:,k] . b'                     [9]
//   ws_k = sum_c Wsp[c,k]                    [9]
// ---------------------------------------------------------------------------
__global__ __launch_bounds__(640) void kprecomp(
    const float* __restrict__ W0, const float* __restrict__ b0,
    const float* __restrict__ W2, const float* __restrict__ b2,
    const float* __restrict__ Wsp,
    float* __restrict__ M0, float* __restrict__ A1g,
    float* __restrict__ sb, float* __restrict__ wsum) {
  __shared__ float A1s[9 * kCL];
  __shared__ float bp[kCL];
  const int t = threadIdx.x;
  if (t < kCL) {
    float s = b2[t];
    for (int j = 0; j < kCL; ++j) s += W2[t * kCL + j] * b0[j];
    bp[t] = s;
  }
  if (t < 9 * kCL) {
    int k = t / kCL, j = t - k * kCL;
    float s = 0.f;
    for (int c = 0; c < kCL; ++c) s += Wsp[c * 9 + k] * W2[c * kCL + j];
    A1s[t] = s;
    A1g[t] = s;
  }
  __syncthreads();
  if (t < 9 * 35) {
    int k = t / 35, i = t - k * 35;
    float s = 0.f;
    for (int j = 0; j < kCL; ++j) s += A1s[k * kCL + j] * W0[j * 35 + i];
    M0[t] = s;
  }
  if (t >= 576 && t < 585) {
    int k = t - 576;
    float s = 0.f;
    for (int c = 0; c < kCL; ++c) s += Wsp[c * 9 + k] * bp[c];
    sb[k] = s;
  }
  if (t >= 592 && t < 601) {
    int k = t - 592;
    float s = 0.f;
    for (int c = 0; c < kCL; ++c) s += Wsp[c * 9 + k];
    wsum[k] = s;
  }
}

// ---------------------------------------------------------------------------
// gate field, float4 over pixels: g[b,p] = b3 + W3 . x_rgb[b,:,p]
// ---------------------------------------------------------------------------
__global__ __launch_bounds__(256) void kgate(const float* __restrict__ x_rgb,
                                             const float* __restrict__ W3,
                                             const float* __restrict__ b3,
                                             float* __restrict__ g) {
  const int j = blockIdx.x * 256 + threadIdx.x;  // [0, B*kHW4)
  const int b = j / kHW4;
  const int p4 = j - b * kHW4;
  const float4* xr = (const float4*)(x_rgb + (size_t)b * kC * kHW) + p4;
  float bias = b3[0];
  float4 acc = make_float4(bias, bias, bias, bias);
#pragma unroll
  for (int c = 0; c < kC; ++c) {
    float wv = W3[c];
    float4 x4 = xr[(size_t)c * kHW4];
    acc.x += wv * x4.x;
    acc.y += wv * x4.y;
    acc.z += wv * x4.z;
    acc.w += wv * x4.w;
  }
  ((float4*)g)[j] = acc;
}

// ---------------------------------------------------------------------------
// per-SOURCE-pixel tap projection (gathers happen once, not 9x):
//   y[k][pix] = wsum[k]*g[pix] + sb[k]
//             + [win0>=0] M0[k].p0(pix) + [win1>=0] A1[k].p1(pix)
// ---------------------------------------------------------------------------
__global__ __launch_bounds__(256) void kgy(
    const float* __restrict__ g,
    const int* __restrict__ win0, const int* __restrict__ win1,
    const float* __restrict__ feat0, const float* __restrict__ vox0,
    const float* __restrict__ feat1, const float* __restrict__ vox1,
    const float* __restrict__ M0, const float* __restrict__ A1,
    const float* __restrict__ sb, const float* __restrict__ wsum,
    float* __restrict__ y) {
  const int pix = blockIdx.x * 256 + threadIdx.x;
  const int b = pix / kHW;
  const float gv = g[pix];
  float yk[9];
#pragma unroll
  for (int k = 0; k < 9; ++k) yk[k] = wsum[k] * gv + sb[k];

  const int w0 = win0[pix];
  if (w0 >= 0) {
    const float* f0 = feat0 + ((size_t)b * kN0 + w0) * kC0;
#pragma unroll
    for (int i = 0; i < kC0; ++i) {
      float v = f0[i];
#pragma unroll
      for (int k = 0; k < 9; ++k) yk[k] += M0[k * 35 + i] * v;
    }
    const float* v0 = vox0 + ((size_t)b * kN0 + w0) * 3;
#pragma unroll
    for (int i = 0; i < 3; ++i) {
      float v = v0[i];
#pragma unroll
      for (int k = 0; k < 9; ++k) yk[k] += M0[k * 35 + kC0 + i] * v;
    }
  }
  const int w1 = win1[pix];
  if (w1 >= 0) {
    const float* f1 = feat1 + ((size_t)b * kN1 + w1) * kC1;
#pragma unroll
    for (int i = 0; i < kC1; ++i) {
      float v = f1[i];
#pragma unroll
      for (int k = 0; k < 9; ++k) yk[k] += A1[k * kCL + i] * v;
    }
    const float* v1 = vox1 + ((size_t)b * kN1 + w1) * 3;
#pragma unroll
    for (int i = 0; i < 3; ++i) {
      float v = v1[i];
#pragma unroll
      for (int k = 0; k < 9; ++k) yk[k] += A1[k * kCL + kC1 + i] * v;
    }
  }
#pragma unroll
  for (int k = 0; k < 9; ++k) y[(size_t)k * kBHW + pix] = yk[k];
}

// ---------------------------------------------------------------------------
// stencil-sum of the 9 planes (coalesced) + sigmoid:
//   att[p] = sigmoid( bsp + sum_{valid k} y[k][p + off_k] )
// ---------------------------------------------------------------------------
__global__ __launch_bounds__(256) void katt2(const float* __restrict__ y,
                                             const float* __restrict__ bsp,
                                             float* __restrict__ att) {
  const int pix = blockIdx.x * 256 + threadIdx.x;
  const int b = pix / kHW;
  const int p = pix - b * kHW;
  const int h = p / kW;
  const int w = p - h * kW;

  float logit = bsp[0];
#pragma unroll
  for (int dh = -1; dh <= 1; ++dh) {
    const int hh = h + dh;
    if (hh < 0 || hh >= kH) continue;
#pragma unroll
    for (int dw = -1; dw <= 1; ++dw) {
      const int ww = w + dw;
      if (ww < 0 || ww >= kW) continue;
      const int k = (dh + 1) * 3 + (dw + 1);
      logit += y[(size_t)k * kBHW + b * kHW + hh * kW + ww];
    }
  }
  att[pix] = 1.f / (1.f + __expf(-logit));
}

// ---------------------------------------------------------------------------
// out[b,c,p] = x_rgb[b,c,p] * att[b,p], float4-vectorized stream
// ---------------------------------------------------------------------------
__global__ __launch_bounds__(256) void kmul(const float* __restrict__ x_rgb,
                                            const float* __restrict__ att,
                                            float* __restrict__ out) {
  const int i = blockIdx.x * 256 + threadIdx.x;  // [0, B*C*kHW4)
  const int b = i / (kC * kHW4);
  const int r = i - b * (kC * kHW4);
  const int p4 = r % kHW4;
  float4 a4 = ((const float4*)att)[b * kHW4 + p4];
  float4 x4 = ((const float4*)x_rgb)[i];
  x4.x *= a4.x;
  x4.y *= a4.y;
  x4.z *= a4.z;
  x4.w *= a4.w;
  ((float4*)out)[i] = x4;
}

}  // namespace

extern "C" void kernel_launch(void* const* d_in, const int* in_sizes, int n_in,
                              void* d_out, int out_size, void* d_ws,
                              size_t ws_size, hipStream_t stream) {
  const float* x_rgb = (const float*)d_in[0];
  const float* feat0 = (const float*)d_in[1];
  const float* coor0 = (const float*)d_in[2];
  const float* vox0 = (const float*)d_in[3];
  const float* feat1 = (const float*)d_in[4];
  const float* coor1 = (const float*)d_in[5];
  const float* vox1 = (const float*)d_in[6];
  const float* W0 = (const float*)d_in[7];
  const float* b0 = (const float*)d_in[8];
  const float* W2 = (const float*)d_in[9];
  const float* b2 = (const float*)d_in[10];
  const float* W3 = (const float*)d_in[11];
  const float* b3 = (const float*)d_in[12];
  const float* Wsp = (const float*)d_in[13];
  const float* bsp = (const float*)d_in[14];
  float* out = (float*)d_out;

  // workspace layout (all 16B aligned):
  //   g[BHW] | att[BHW] | y[9*BHW] | win0[BHW] | win1[BHW] | M0 | A1 | sb | ws
  float* g = (float*)d_ws;
  float* att = g + (size_t)kBHW;
  float* y = att + (size_t)kBHW;
  int* win0 = (int*)(y + (size_t)9 * kBHW);
  int* win1 = win0 + (size_t)kBHW;
  float* M0 = (float*)(win1 + (size_t)kBHW);
  float* A1 = M0 + 9 * 35;
  float* sb = A1 + 9 * kCL;
  float* wsum = sb + 9;

  const int n4 = 2 * kBHW / 4;  // 122880 int4s
  kwinit<<<(n4 + 255) / 256, 256, 0, stream>>>((int4*)win0, n4);
  const int npts = kB * (kN0 + kN1);
  scatter_win<<<(npts + 255) / 256, 256, 0, stream>>>(coor0, coor1, win0,
                                                      win1);
  kprecomp<<<1, 640, 0, stream>>>(W0, b0, W2, b2, Wsp, M0, A1, sb, wsum);
  kgate<<<kB * kHW4 / 256, 256, 0, stream>>>(x_rgb, W3, b3, g);
  kgy<<<kBHW / 256, 256, 0, stream>>>(g, win0, win1, feat0, vox0, feat1, vox1,
                                      M0, A1, sb, wsum, y);
  katt2<<<kBHW / 256, 256, 0, stream>>>(y, bsp, att);
  kmul<<<kB * kC * kHW4 / 256, 256, 0, stream>>>(x_rgb, att, out);
}